// Round 2
// baseline (4133.768 us; speedup 1.0000x reference)
//
#include <hip/hip_runtime.h>
#include <math.h>

#define N_NODES 50000
#define N_EDGES 500000
#define IN_DIM  128
#define NH      8
#define HD      16
#define OUTD    128   // NH*HD
#define CLAMP_V 5.0f

typedef unsigned short ushort_t;
typedef short bf16x8 __attribute__((ext_vector_type(8)));
typedef float f32x16 __attribute__((ext_vector_type(16)));

__device__ __forceinline__ ushort_t f2bf(float f) {
    uint32_t u = __float_as_uint(f);
    u += 0x7fffu + ((u >> 16) & 1u);          // round-to-nearest-even
    return (ushort_t)(u >> 16);
}
__device__ __forceinline__ float bf2f(ushort_t h) {
    return __uint_as_float(((uint32_t)h) << 16);
}

// Load 8 contiguous f32 and split into bf16 hi/lo fragments (in registers).
__device__ __forceinline__ void load_cvt8(const float* p, bool valid,
                                          bf16x8& hv, bf16x8& lv) {
    float v[8];
    if (valid) {
        float4 a = *(const float4*)p, b = *(const float4*)(p + 4);
        v[0]=a.x; v[1]=a.y; v[2]=a.z; v[3]=a.w;
        v[4]=b.x; v[5]=b.y; v[6]=b.z; v[7]=b.w;
    } else {
        #pragma unroll
        for (int j = 0; j < 8; ++j) v[j] = 0.f;
    }
    #pragma unroll
    for (int j = 0; j < 8; ++j) {
        ushort_t h = f2bf(v[j]);
        hv[j] = (short)h;
        lv[j] = (short)f2bf(v[j] - bf2f(h));
    }
}

// ---------------------------------------------------------------------------
// Kernel 0: pack a [128][C] f32 weight into MFMA B-fragment order, bf16 hi/lo.
// Fragment (cb, ks): lane l holds W[k = ks*16 + (l>>5)*8 + j][col = cb*32 + (l&31)],
// stored at ((cb*8 + ks)*64 + l)*8 + j  -> wave loads = coalesced dwordx4.
// ---------------------------------------------------------------------------
__global__ __launch_bounds__(256) void pack_w_kernel(
    const float* __restrict__ W, int C,
    ushort_t* __restrict__ hi, ushort_t* __restrict__ lo)
{
    int tid = blockIdx.x * 256 + threadIdx.x;
    int l  = tid & 63;
    int ks = (tid >> 6) & 7;
    int cb = tid >> 9;
    if (cb * 32 >= C) return;
    int col = cb * 32 + (l & 31);
    int k0  = ks * 16 + ((l >> 5) << 3);
    size_t ob = ((size_t)(cb * 8 + ks) * 64 + l) * 8;
    #pragma unroll
    for (int j = 0; j < 8; ++j) {
        float v = W[(size_t)(k0 + j) * C + col];
        ushort_t h = f2bf(v);
        hi[ob + j] = h;
        lo[ob + j] = f2bf(v - bf2f(h));
    }
}

// ---------------------------------------------------------------------------
// Kernel 1: node GEMM via MFMA, fragment-direct (no LDS, no barriers).
// Tile 128 nodes x 128 cols; 4 waves (2x2), per wave 64x64 = 2x2 frags.
// grid.y selects which of Q/K/V.  hi/lo split: 3 MFMAs per frag pair.
// ---------------------------------------------------------------------------
__global__ __launch_bounds__(256) void node_mfma_kernel(
    const float* __restrict__ x,
    const ushort_t* __restrict__ WQh, const ushort_t* __restrict__ WQl,
    const ushort_t* __restrict__ WKh, const ushort_t* __restrict__ WKl,
    const ushort_t* __restrict__ WVh, const ushort_t* __restrict__ WVl,
    const float* __restrict__ bQ, const float* __restrict__ bK,
    const float* __restrict__ bV,
    float* __restrict__ Qs, float* __restrict__ Kn, float* __restrict__ Vn)
{
    const int t = threadIdx.x, lane = t & 63, w = t >> 6;
    const int wi = w >> 1, wjc = w & 1;
    const int n0 = blockIdx.x * 128;
    const int which = blockIdx.y;
    const ushort_t* Whi = (which == 0) ? WQh : (which == 1 ? WKh : WVh);
    const ushort_t* Wlo = (which == 0) ? WQl : (which == 1 ? WKl : WVl);
    const float*    bias= (which == 0) ? bQ  : (which == 1 ? bK  : bV);
    float*          out = (which == 0) ? Qs  : (which == 1 ? Kn  : Vn);

    const int lrow = lane & 31, lk = (lane >> 5) << 3;

    f32x16 acc[2][2];
    #pragma unroll
    for (int i = 0; i < 2; ++i)
        #pragma unroll
        for (int j = 0; j < 2; ++j)
            #pragma unroll
            for (int g = 0; g < 16; ++g) acc[i][j][g] = 0.f;

    #pragma unroll
    for (int ks = 0; ks < 8; ++ks) {
        bf16x8 ah[2], al[2];
        #pragma unroll
        for (int i = 0; i < 2; ++i) {
            int row = n0 + wi * 64 + i * 32 + lrow;
            load_cvt8(x + (size_t)row * IN_DIM + ks * 16 + lk, row < N_NODES,
                      ah[i], al[i]);
        }
        #pragma unroll
        for (int jf = 0; jf < 2; ++jf) {
            const int cb = wjc * 2 + jf;
            size_t ob = ((size_t)(cb * 8 + ks) * 64 + lane) * 8;
            bf16x8 bh = *(const bf16x8*)(Whi + ob);
            bf16x8 bl = *(const bf16x8*)(Wlo + ob);
            #pragma unroll
            for (int i = 0; i < 2; ++i) {
                acc[i][jf] = __builtin_amdgcn_mfma_f32_32x32x16_bf16(ah[i], bh, acc[i][jf], 0, 0, 0);
                acc[i][jf] = __builtin_amdgcn_mfma_f32_32x32x16_bf16(ah[i], bl, acc[i][jf], 0, 0, 0);
                acc[i][jf] = __builtin_amdgcn_mfma_f32_32x32x16_bf16(al[i], bh, acc[i][jf], 0, 0, 0);
            }
        }
    }

    float bv[2];
    #pragma unroll
    for (int jf = 0; jf < 2; ++jf) bv[jf] = bias[wjc * 64 + jf * 32 + lrow];

    #pragma unroll
    for (int i = 0; i < 2; ++i)
        #pragma unroll
        for (int jf = 0; jf < 2; ++jf)
            #pragma unroll
            for (int g = 0; g < 16; ++g) {
                int row = n0 + wi * 64 + i * 32 + (g & 3) + 8 * (g >> 2) + 4 * (lane >> 5);
                if (row < N_NODES)
                    out[(size_t)row * OUTD + wjc * 64 + jf * 32 + lrow] = acc[i][jf][g] + bv[jf];
            }
}

// ---------------------------------------------------------------------------
// Kernel 2: edge GEMM (MFMA, fragment-direct, zero-LDS main loop) + FUSED
// epilogue: conn, score, exp, and UNNORMALIZED scatter of
//   ex * (Vh[src] + conn @ VeRow)  into VoAcc,  ex into denom.
// Normalization (div by denom) happens in final_kernel:  sum(ex/den * X) =
// sum(ex*X)/den.  This deletes the separate scatter pass + conn re-read and
// halves the atomic count by folding VeRow per-edge.
// Tile: 64 edges x 256 cols (all 8 heads).  4 waves: wave w = (wi=w>>1 rows,
// wj=w&1 col-half), acc 1x4 frags.  Epilogue: lane = edge, wave = head {w, w+4}.
// LDS: 64KB f32 stash [64][256], element-XOR swizzled (c ^ (r&31)) ->
// conflict-free writes (consecutive c) and reads (bank = d ^ r, all 32).
// ---------------------------------------------------------------------------
__global__ __launch_bounds__(256) void edge_mfma_kernel(
    const float* __restrict__ edge_attr,
    const int*   __restrict__ edge_index,
    const ushort_t* __restrict__ WEh, const ushort_t* __restrict__ WEl,
    const float* __restrict__ bE, const float* __restrict__ Aw,
    const float* __restrict__ Qs, const float* __restrict__ Kn,
    const float* __restrict__ Vn, const float* __restrict__ VeRow,
    float* __restrict__ conn_out,
    float* __restrict__ VoAcc,
    float* __restrict__ denom)
{
    __shared__ float stash[64 * 256];

    const int t = threadIdx.x, lane = t & 63, w = t >> 6;
    const int wi = w >> 1, wj = w & 1;
    const int e0 = blockIdx.x * 64;

    const int lrow = lane & 31, lk = (lane >> 5) << 3;
    const int arow = e0 + wi * 32 + lrow;
    const bool rvalid = arow < N_EDGES;
    const float* ap = edge_attr + (size_t)arow * IN_DIM;

    f32x16 acc[4];
    #pragma unroll
    for (int jf = 0; jf < 4; ++jf)
        #pragma unroll
        for (int g = 0; g < 16; ++g) acc[jf][g] = 0.f;

    #pragma unroll
    for (int ks = 0; ks < 8; ++ks) {
        bf16x8 ah, al;
        load_cvt8(ap + ks * 16 + lk, rvalid, ah, al);
        #pragma unroll
        for (int jf = 0; jf < 4; ++jf) {
            const int cb = wj * 4 + jf;
            size_t ob = ((size_t)(cb * 8 + ks) * 64 + lane) * 8;
            bf16x8 bh = *(const bf16x8*)(WEh + ob);
            bf16x8 bl = *(const bf16x8*)(WEl + ob);
            acc[jf] = __builtin_amdgcn_mfma_f32_32x32x16_bf16(ah, bh, acc[jf], 0, 0, 0);
            acc[jf] = __builtin_amdgcn_mfma_f32_32x32x16_bf16(ah, bl, acc[jf], 0, 0, 0);
            acc[jf] = __builtin_amdgcn_mfma_f32_32x32x16_bf16(al, bh, acc[jf], 0, 0, 0);
        }
    }

    // stash Ex (+bias) into swizzled LDS (waves write disjoint regions)
    float bv[4];
    #pragma unroll
    for (int jf = 0; jf < 4; ++jf) bv[jf] = bE[wj * 128 + jf * 32 + lrow];
    #pragma unroll
    for (int jf = 0; jf < 4; ++jf)
        #pragma unroll
        for (int g = 0; g < 16; ++g) {
            int r = wi * 32 + (g & 3) + 8 * (g >> 2) + 4 * (lane >> 5);
            int c = wj * 128 + jf * 32 + lrow;
            stash[r * 256 + (c ^ (r & 31))] = acc[jf][g] + bv[jf];
        }
    __syncthreads();

    // ---- fused epilogue: lane = edge r, wave w handles heads w and w+4
    const int r = lane;
    const int e = e0 + r;
    const bool valid = e < N_EDGES;
    const int src = valid ? edge_index[e] : 0;
    const int dst = valid ? edge_index[N_EDGES + e] : 0;

    #pragma unroll
    for (int hp = 0; hp < 2; ++hp) {
        const int h = w + hp * 4;

        float kq[16];
        {
            const float4* K4 = (const float4*)(Kn + (size_t)src * OUTD + h * HD);
            const float4* Q4 = (const float4*)(Qs + (size_t)dst * OUTD + h * HD);
            #pragma unroll
            for (int i = 0; i < 4; ++i) {
                float4 kk = K4[i], qq = Q4[i];
                kq[i * 4 + 0] = kk.x + qq.x;
                kq[i * 4 + 1] = kk.y + qq.y;
                kq[i * 4 + 2] = kk.z + qq.z;
                kq[i * 4 + 3] = kk.w + qq.w;
            }
        }

        float cv[16];
        float score = 0.f;
        #pragma unroll
        for (int d = 0; d < 16; ++d) {
            float x1 = stash[r * 256 + ((h * 32 + d)      ^ (r & 31))];
            float x2 = stash[r * 256 + ((h * 32 + 16 + d) ^ (r & 31))];
            float s2 = x1 * x2;
            float sq = (s2 >= 0.f) ? sqrtf(s2) : -sqrtf(-s2);
            float c  = kq[d] + sq;
            cv[d] = c;
            score += c * Aw[d * NH + h];
        }

        if (valid) {
            float4* co = (float4*)(conn_out + (size_t)e * OUTD + h * HD);
            #pragma unroll
            for (int i = 0; i < 4; ++i)
                co[i] = make_float4(cv[i * 4 + 0], cv[i * 4 + 1],
                                    cv[i * 4 + 2], cv[i * 4 + 3]);
        }

        score = fminf(fmaxf(score, -CLAMP_V), CLAMP_V);
        const float ex = __expf(score);

        // msg = Vh[src] + conn @ VeRow   (per head, 16-wide)
        float outv[16];
        {
            const float4* V4 = (const float4*)(Vn + (size_t)src * OUTD + h * HD);
            #pragma unroll
            for (int i = 0; i < 4; ++i) {
                float4 vv = V4[i];
                outv[i * 4 + 0] = vv.x; outv[i * 4 + 1] = vv.y;
                outv[i * 4 + 2] = vv.z; outv[i * 4 + 3] = vv.w;
            }
        }
        #pragma unroll
        for (int d = 0; d < 16; ++d) {
            const float4* vr = (const float4*)(VeRow + d * OUTD + h * HD);
            float cvd = cv[d];
            float4 v0 = vr[0], v1 = vr[1], v2 = vr[2], v3 = vr[3];
            outv[0]  += cvd * v0.x; outv[1]  += cvd * v0.y;
            outv[2]  += cvd * v0.z; outv[3]  += cvd * v0.w;
            outv[4]  += cvd * v1.x; outv[5]  += cvd * v1.y;
            outv[6]  += cvd * v1.z; outv[7]  += cvd * v1.w;
            outv[8]  += cvd * v2.x; outv[9]  += cvd * v2.y;
            outv[10] += cvd * v2.z; outv[11] += cvd * v2.w;
            outv[12] += cvd * v3.x; outv[13] += cvd * v3.y;
            outv[14] += cvd * v3.z; outv[15] += cvd * v3.w;
        }

        if (valid) {
            atomicAdd(denom + (size_t)dst * NH + h, ex);
            float* vp = VoAcc + (size_t)dst * OUTD + h * HD;
            #pragma unroll
            for (int c = 0; c < 16; ++c)
                atomicAdd(vp + c, ex * outv[c]);
        }
    }
}

// ---------------------------------------------------------------------------
// Kernel 3: finalize.  Vo = Qs + VoAcc / (denom + 1e-16).
// ---------------------------------------------------------------------------
__global__ __launch_bounds__(256) void final_kernel(
    const float* __restrict__ Qs, const float* __restrict__ denom,
    float* __restrict__ Vo)
{
    int idx = blockIdx.x * 256 + threadIdx.x;     // one float4 each
    if (idx >= N_NODES * 32) return;
    int n  = idx >> 5;
    int c4 = (idx & 31) * 4;
    int h  = c4 >> 4;
    float inv = 1.f / (denom[(size_t)n * NH + h] + 1e-16f);
    float4 a = *(float4*)(Vo + (size_t)n * OUTD + c4);
    const float4 q = *(const float4*)(Qs + (size_t)n * OUTD + c4);
    a.x = q.x + a.x * inv;
    a.y = q.y + a.y * inv;
    a.z = q.z + a.z * inv;
    a.w = q.w + a.w * inv;
    *(float4*)(Vo + (size_t)n * OUTD + c4) = a;
}

// ---------------------------------------------------------------------------
extern "C" void kernel_launch(void* const* d_in, const int* in_sizes, int n_in,
                              void* d_out, int out_size, void* d_ws, size_t ws_size,
                              hipStream_t stream)
{
    const float* x         = (const float*)d_in[0];
    const float* edge_attr = (const float*)d_in[1];
    const int*   edge_index= (const int*)  d_in[2];
    const float* WQ = (const float*)d_in[3];
    const float* bQ = (const float*)d_in[4];
    const float* WK = (const float*)d_in[5];
    const float* bK = (const float*)d_in[6];
    const float* WE = (const float*)d_in[7];
    const float* bE = (const float*)d_in[8];
    const float* WV = (const float*)d_in[9];
    const float* bV = (const float*)d_in[10];
    const float* Aw = (const float*)d_in[11];
    const float* VeRow = (const float*)d_in[12];

    float* Vo   = (float*)d_out;                       // [N,128] accumulator then final
    float* conn = Vo + (size_t)N_NODES * OUTD;         // [E,128]

    float* ws    = (float*)d_ws;
    float* Qs    = ws;                                 // N*128
    float* Kn    = Qs + (size_t)N_NODES * OUTD;        // N*128
    float* Vn    = Kn + (size_t)N_NODES * OUTD;        // N*128
    float* denom = Vn + (size_t)N_NODES * OUTD;        // N*8
    ushort_t* WQh = (ushort_t*)(denom + (size_t)N_NODES * NH);
    ushort_t* WQl = WQh + 16384;
    ushort_t* WKh = WQl + 16384;
    ushort_t* WKl = WKh + 16384;
    ushort_t* WVh = WKl + 16384;
    ushort_t* WVl = WVh + 16384;
    ushort_t* WEh = WVl + 16384;
    ushort_t* WEl = WEh + 32768;

    hipMemsetAsync(Vo,    0, (size_t)N_NODES * OUTD * sizeof(float), stream);
    hipMemsetAsync(denom, 0, (size_t)N_NODES * NH   * sizeof(float), stream);

    pack_w_kernel<<<8,  256, 0, stream>>>(WQ, 128, WQh, WQl);
    pack_w_kernel<<<8,  256, 0, stream>>>(WK, 128, WKh, WKl);
    pack_w_kernel<<<8,  256, 0, stream>>>(WV, 128, WVh, WVl);
    pack_w_kernel<<<16, 256, 0, stream>>>(WE, 256, WEh, WEl);

    dim3 g1((N_NODES + 127) / 128, 3);                 // 391 x 3
    node_mfma_kernel<<<g1, 256, 0, stream>>>(x, WQh, WQl, WKh, WKl, WVh, WVl,
                                             bQ, bK, bV, Qs, Kn, Vn);

    const int nblk = (N_EDGES + 63) / 64;              // 7813
    edge_mfma_kernel<<<nblk, 256, 0, stream>>>(edge_attr, edge_index, WEh, WEl,
                                               bE, Aw, Qs, Kn, Vn, VeRow,
                                               conn, Vo, denom);

    final_kernel<<<(N_NODES * 32 + 255) / 256, 256, 0, stream>>>(Qs, denom, Vo);
}